// Round 2
// baseline (1052.819 us; speedup 1.0000x reference)
//
#include <hip/hip_runtime.h>
#include <hip/hip_bf16.h>

// Problem shapes (fixed by setup_inputs)
constexpr int B_  = 4;
constexpr int N_  = 2048;
constexpr int C_  = 1024;
constexpr int H_  = 16;
constexpr int HD  = 64;    // head dim
constexpr int LR  = 20;    // low rank
constexpr int RS  = 200;   // subsample length R

__device__ __forceinline__ float b2f_raw(unsigned short u) {
    union { unsigned int i; float f; } v;
    v.i = ((unsigned int)u) << 16;
    return v.f;
}

// Generic element load/store: BF=true -> bf16 buffer, else fp32 buffer.
template <bool BF>
__device__ __forceinline__ float ldval(const void* p, size_t i) {
    if constexpr (BF) return b2f_raw(((const unsigned short*)p)[i]);
    else              return ((const float*)p)[i];
}

template <bool BF>
__device__ __forceinline__ void ld4(const void* p, size_t i, float out[4]) {
    if constexpr (BF) {
        const ushort4 r = *reinterpret_cast<const ushort4*>((const unsigned short*)p + i);
        out[0] = b2f_raw(r.x); out[1] = b2f_raw(r.y);
        out[2] = b2f_raw(r.z); out[3] = b2f_raw(r.w);
    } else {
        const float4 r = *reinterpret_cast<const float4*>((const float*)p + i);
        out[0] = r.x; out[1] = r.y; out[2] = r.z; out[3] = r.w;
    }
}

template <bool BF>
__device__ __forceinline__ void stval(void* p, size_t i, float v) {
    if constexpr (BF) ((__hip_bfloat16*)p)[i] = __float2bfloat16(v);
    else              ((float*)p)[i] = v;
}

// ---------------------------------------------------------------------------
// dtype detection: inspect low 16 bits of first 1024 words of x.
// bf16 data -> low half is a real bf16 sample (exponent in [103,140] ~always).
// fp32 data -> low half is uniform mantissa bits (~15% in range).
// ---------------------------------------------------------------------------
__global__ __launch_bounds__(256)
void detect_kernel(const unsigned int* __restrict__ x, int* __restrict__ flag) {
    const int t = threadIdx.x;
    int cnt = 0;
    for (int i = t; i < 1024; i += 256) {
        const unsigned int w = x[i];
        const unsigned int e = (w >> 7) & 0xFFu;  // exponent of LOW bf16 half
        cnt += (e >= 103u && e <= 140u) ? 1 : 0;
    }
    __shared__ int s[256];
    s[t] = cnt;
    __syncthreads();
    for (int off = 128; off > 0; off >>= 1) {
        if (t < off) s[t] += s[t + off];
        __syncthreads();
    }
    if (t == 0) *flag = (s[0] > 512) ? 1 : 0;  // 1 = bf16 inputs, 0 = fp32
}

// ---------------------------------------------------------------------------
// GEMM (NT): out[m,n] = sum_k A[m*K+k] * W[n*K+k] (+ bias[n]); fp32 accum.
// BM=BN=64, BK=16, 256 threads, 4x4 per thread. M,N,K multiples of 64.
// ---------------------------------------------------------------------------
template <bool ABF, bool WBF, bool BBF, bool OBF, bool HAS_BIAS>
__device__ void gemm_body(const void* __restrict__ A,
                          const void* __restrict__ W,
                          const void* __restrict__ bias,
                          void* __restrict__ out,
                          int M, int N, int K) {
    constexpr int BM = 64, BN = 64, BK = 16;
    __shared__ float As[BK][BM];
    __shared__ float Bs[BK][BN];

    const int t  = threadIdx.x;
    const int tx = t & 15;
    const int ty = t >> 4;
    const int m0 = blockIdx.y * BM;
    const int n0 = blockIdx.x * BN;

    const int lm = t >> 2;
    const int lk = (t & 3) * 4;

    float acc[4][4] = {};

    for (int k0 = 0; k0 < K; k0 += BK) {
        {
            float ra[4], rb[4];
            ld4<ABF>(A, (size_t)(m0 + lm) * K + (k0 + lk), ra);
            ld4<WBF>(W, (size_t)(n0 + lm) * K + (k0 + lk), rb);
            #pragma unroll
            for (int i = 0; i < 4; ++i) {
                As[lk + i][lm] = ra[i];
                Bs[lk + i][lm] = rb[i];
            }
        }
        __syncthreads();

        #pragma unroll
        for (int kk = 0; kk < BK; ++kk) {
            float a[4], b[4];
            #pragma unroll
            for (int i = 0; i < 4; ++i) a[i] = As[kk][ty * 4 + i];
            #pragma unroll
            for (int j = 0; j < 4; ++j) b[j] = Bs[kk][tx * 4 + j];
            #pragma unroll
            for (int i = 0; i < 4; ++i)
                #pragma unroll
                for (int j = 0; j < 4; ++j)
                    acc[i][j] += a[i] * b[j];
        }
        __syncthreads();
    }

    #pragma unroll
    for (int i = 0; i < 4; ++i) {
        const int m = m0 + ty * 4 + i;
        #pragma unroll
        for (int j = 0; j < 4; ++j) {
            const int n = n0 + tx * 4 + j;
            float v = acc[i][j];
            if constexpr (HAS_BIAS) v += ldval<BBF>(bias, n);
            stval<OBF>(out, (size_t)m * N + n, v);
        }
    }
}

// gemm1: qk = x @ qk_w^T ; inputs follow flag, output fixed bf16 (internal)
__global__ __launch_bounds__(256)
void gemm1_kernel(const int* __restrict__ flag,
                  const void* __restrict__ x, const void* __restrict__ qkw,
                  __hip_bfloat16* __restrict__ qk) {
    if (*flag) gemm_body<true, true, false, true, false>(x, qkw, nullptr, qk, B_ * N_, 2 * C_, C_);
    else       gemm_body<false, false, false, true, false>(x, qkw, nullptr, qk, B_ * N_, 2 * C_, C_);
}

// gemm2: out = attn @ proj_w^T + proj_b ; A fixed bf16, W/bias/out follow flag
__global__ __launch_bounds__(256)
void gemm2_kernel(const int* __restrict__ flag,
                  const __hip_bfloat16* __restrict__ attn,
                  const void* __restrict__ pw, const void* __restrict__ pb,
                  void* __restrict__ out) {
    if (*flag) gemm_body<true, true, true, true, true>(attn, pw, pb, out, B_ * N_, C_, C_);
    else       gemm_body<true, false, false, false, true>(attn, pw, pb, out, B_ * N_, C_, C_);
}

// ---------------------------------------------------------------------------
// gen_weights: we_b[b,h,d,e] = sum_r x[b, idx[r], h*64+d] * we[h,r,e]
// idx[r] = (r*(N-1))/(R-1) exactly (trunc linspace).
// ---------------------------------------------------------------------------
template <bool BF>
__device__ void genw_body(const void* __restrict__ x,
                          const void* __restrict__ we, const void* __restrict__ wr,
                          float* __restrict__ web, float* __restrict__ wrb) {
    const int bh = blockIdx.x;
    const int b  = bh / H_;
    const int h  = bh % H_;
    for (int o = threadIdx.x; o < HD * LR; o += blockDim.x) {
        const int d = o / LR;
        const int e = o % LR;
        float acce = 0.f, accr = 0.f;
        for (int r = 0; r < RS; ++r) {
            const int ir = (r * (N_ - 1)) / (RS - 1);
            const float xv = ldval<BF>(x, ((size_t)b * N_ + ir) * C_ + h * HD + d);
            acce += xv * ldval<BF>(we, ((size_t)h * RS + r) * LR + e);
            accr += xv * ldval<BF>(wr, ((size_t)h * RS + r) * LR + e);
        }
        web[(size_t)bh * HD * LR + o] = acce;
        wrb[(size_t)bh * HD * LR + o] = accr;
    }
}

__global__ __launch_bounds__(256)
void genw_kernel(const int* __restrict__ flag,
                 const void* __restrict__ x,
                 const void* __restrict__ we, const void* __restrict__ wr,
                 float* __restrict__ web, float* __restrict__ wrb) {
    if (*flag) genw_body<true>(x, we, wr, web, wrb);
    else       genw_body<false>(x, we, wr, web, wrb);
}

// ---------------------------------------------------------------------------
// Fused per-(b,h,n): l2norm(q), l2norm(k) -> lr-scores -> cw projection.
// One wave (64 lanes) per (b,h,n); lane = head-dim index.
// qk and attn are internal bf16; cw_w/cw_b follow flag.
// ---------------------------------------------------------------------------
template <bool BF>
__device__ void score_body(const __hip_bfloat16* __restrict__ qk,
                           const float* __restrict__ web,
                           const float* __restrict__ wrb,
                           const void* __restrict__ cw_w,
                           const void* __restrict__ cw_b,
                           __hip_bfloat16* __restrict__ attn) {
    const int gid  = blockIdx.x;      // bh * N_ + n
    const int n    = gid % N_;
    const int bh   = gid / N_;
    const int h    = bh % H_;
    const int b    = bh / H_;
    const int lane = threadIdx.x;

    const size_t rowq = ((size_t)(b * N_ + n)) * (2 * C_) + h * HD + lane;
    const float qv = __bfloat162float(qk[rowq]);
    const float kv = __bfloat162float(qk[rowq + C_]);

    float sq = qv * qv, sk = kv * kv;
    #pragma unroll
    for (int m = 1; m < 64; m <<= 1) {
        sq += __shfl_xor(sq, m, 64);
        sk += __shfl_xor(sk, m, 64);
    }
    const float qn = qv / fmaxf(sqrtf(sq), 1e-12f);
    const float kn = kv / fmaxf(sqrtf(sk), 1e-12f);

    __shared__ float qs[HD], ks[HD], sc[2 * LR];
    qs[lane] = qn;
    ks[lane] = kn;
    __syncthreads();

    const float* wb = web + (size_t)bh * HD * LR;
    const float* rb = wrb + (size_t)bh * HD * LR;
    if (lane < LR) {
        float s = 0.f;
        #pragma unroll 8
        for (int d = 0; d < HD; ++d) s += qs[d] * wb[d * LR + lane];
        sc[lane] = s;
    } else if (lane >= 32 && lane < 32 + LR) {
        const int e = lane - 32;
        float s = 0.f;
        #pragma unroll 8
        for (int d = 0; d < HD; ++d) s += ks[d] * rb[d * LR + e];
        sc[LR + e] = s;
    }
    __syncthreads();

    float a = ldval<BF>(cw_b, lane);
    #pragma unroll
    for (int e = 0; e < 2 * LR; ++e)
        a += sc[e] * ldval<BF>(cw_w, lane * 2 * LR + e);

    attn[((size_t)(b * N_ + n)) * C_ + h * HD + lane] = __float2bfloat16(a);
}

__global__ __launch_bounds__(64)
void score_attn_kernel(const int* __restrict__ flag,
                       const __hip_bfloat16* __restrict__ qk,
                       const float* __restrict__ web,
                       const float* __restrict__ wrb,
                       const void* __restrict__ cw_w,
                       const void* __restrict__ cw_b,
                       __hip_bfloat16* __restrict__ attn) {
    if (*flag) score_body<true>(qk, web, wrb, cw_w, cw_b, attn);
    else       score_body<false>(qk, web, wrb, cw_w, cw_b, attn);
}

// ---------------------------------------------------------------------------
extern "C" void kernel_launch(void* const* d_in, const int* in_sizes, int n_in,
                              void* d_out, int out_size, void* d_ws, size_t ws_size,
                              hipStream_t stream) {
    const void* x      = d_in[0];
    const void* qk_w   = d_in[1];
    const void* proj_w = d_in[2];
    const void* proj_b = d_in[3];
    const void* we     = d_in[4];
    const void* wr     = d_in[5];
    const void* cw_w   = d_in[6];
    const void* cw_b   = d_in[7];

    char* ws = (char*)d_ws;
    int* flag = (int*)ws;                                             // 16 B slot
    size_t off = 16;
    __hip_bfloat16* qk   = (__hip_bfloat16*)(ws + off);               // [B*N, 2C] bf16: 32 MB
    off += (size_t)B_ * N_ * 2 * C_ * sizeof(__hip_bfloat16);
    __hip_bfloat16* attn = (__hip_bfloat16*)(ws + off);               // [B*N, C] bf16: 16 MB
    off += (size_t)B_ * N_ * C_ * sizeof(__hip_bfloat16);
    float* web = (float*)(ws + off);                                  // [B*H, 64, 20] f32
    off += (size_t)B_ * H_ * HD * LR * sizeof(float);
    float* wrb = (float*)(ws + off);
    (void)ws_size; (void)in_sizes; (void)n_in; (void)out_size;

    const int M = B_ * N_;  // 8192

    // 0) dtype detection (writes flag; all later kernels branch on it)
    detect_kernel<<<1, 256, 0, stream>>>((const unsigned int*)x, flag);

    // 1) qk projection: [M, 2C] = x @ qk_w^T
    gemm1_kernel<<<dim3((2 * C_) / 64, M / 64), 256, 0, stream>>>(flag, x, qk_w, qk);

    // 2) low-rank weight generation (tiny)
    genw_kernel<<<B_ * H_, 256, 0, stream>>>(flag, x, we, wr, web, wrb);

    // 3) fused normalize + scores + cw projection -> attn [B,N,C]
    score_attn_kernel<<<B_ * H_ * N_, 64, 0, stream>>>(flag, qk, web, wrb, cw_w, cw_b, attn);

    // 4) output projection: out = attn @ proj_w^T + proj_b
    gemm2_kernel<<<dim3(C_ / 64, M / 64), 256, 0, stream>>>(flag, attn, proj_w, proj_b, d_out);
}

// Round 3
// 396.453 us; speedup vs baseline: 2.6556x; 2.6556x over previous
//
#include <hip/hip_runtime.h>
#include <hip/hip_bf16.h>

// Problem shapes (fixed by setup_inputs)
constexpr int B_  = 4;
constexpr int N_  = 2048;
constexpr int C_  = 1024;
constexpr int H_  = 16;
constexpr int HD  = 64;    // head dim
constexpr int LR  = 20;    // low rank
constexpr int RS  = 200;   // subsample length R

typedef __attribute__((ext_vector_type(8))) short bf16x8;
typedef __attribute__((ext_vector_type(4))) float f32x4;

__device__ __forceinline__ float b2f_raw(unsigned short u) {
    union { unsigned int i; float f; } v;
    v.i = ((unsigned int)u) << 16;
    return v.f;
}
__device__ __forceinline__ unsigned short f2b(float f) {
    __hip_bfloat16 h = __float2bfloat16(f);
    return *(unsigned short*)&h;
}

// async 16B global->LDS (wave-uniform LDS base; HW scatters lane i at +16*i)
__device__ __forceinline__ void async_load16(const unsigned short* g, unsigned short* l) {
    __builtin_amdgcn_global_load_lds(
        (const __attribute__((address_space(1))) unsigned int*)(const void*)g,
        (__attribute__((address_space(3))) unsigned int*)(void*)l,
        16, 0, 0);
}

// ---------------------------------------------------------------------------
// dtype detection (kept for robustness): low 16 bits of fp32 words are
// uniform mantissa bits; of packed bf16 pairs they are a real bf16 sample.
// ---------------------------------------------------------------------------
__global__ __launch_bounds__(256)
void detect_kernel(const unsigned int* __restrict__ x, int* __restrict__ flag) {
    const int t = threadIdx.x;
    int cnt = 0;
    for (int i = t; i < 1024; i += 256) {
        const unsigned int w = x[i];
        const unsigned int e = (w >> 7) & 0xFFu;
        cnt += (e >= 103u && e <= 140u) ? 1 : 0;
    }
    __shared__ int s[256];
    s[t] = cnt;
    __syncthreads();
    for (int off = 128; off > 0; off >>= 1) {
        if (t < off) s[t] += s[t + off];
        __syncthreads();
    }
    if (t == 0) *flag = (s[0] > 512) ? 1 : 0;  // 1 = bf16 inputs, 0 = fp32
}

// ---------------------------------------------------------------------------
// Convert all 8 inputs to bf16 copies in ws. blockIdx.y selects buffer.
// All sizes are multiples of 4.
// ---------------------------------------------------------------------------
struct CvtArgs {
    const void* src[8];
    unsigned short* dst[8];
    int size[8];
};

__global__ __launch_bounds__(256)
void convert_kernel(const int* __restrict__ flag, CvtArgs args) {
    const int buf = blockIdx.y;
    const int n4 = args.size[buf] >> 2;
    const int stride = gridDim.x * blockDim.x;
    const bool isbf = (*flag != 0);
    for (int i = blockIdx.x * blockDim.x + threadIdx.x; i < n4; i += stride) {
        ushort4 o;
        if (isbf) {
            o = ((const ushort4*)args.src[buf])[i];
        } else {
            const float4 v = ((const float4*)args.src[buf])[i];
            o.x = f2b(v.x); o.y = f2b(v.y); o.z = f2b(v.z); o.w = f2b(v.w);
        }
        ((ushort4*)args.dst[buf])[i] = o;
    }
}

// ---------------------------------------------------------------------------
// MFMA GEMM (NT): out[m,n] = sum_k A[m,k]*W[n,k] (+bias[n]).
// A,W,bias bf16; out bf16 or fp32. 128x128 tile, BK=32, 256 thr (4 waves),
// each wave computes a 64x64 quadrant as 4x4 of 16x16x32 MFMAs.
// LDS tiles are linear [row][k] (global_load_lds constraint: no padding).
// ---------------------------------------------------------------------------
template <bool OBF, bool HAS_BIAS>
__device__ void mfma_gemm_body(const unsigned short* __restrict__ A,
                               const unsigned short* __restrict__ W,
                               const unsigned short* __restrict__ bias,
                               void* __restrict__ out,
                               int M, int N, int K) {
    constexpr int BM = 128, BN = 128, BK = 32;
    __shared__ __align__(16) unsigned short As[BM * BK];  // 8 KB
    __shared__ __align__(16) unsigned short Bs[BN * BK];  // 8 KB

    const int t    = threadIdx.x;
    const int wave = t >> 6;
    const int lane = t & 63;
    const int m0   = blockIdx.y * BM;
    const int n0   = blockIdx.x * BN;

    // staging: chunk c (0..7) = LDS bytes [c*1024,(c+1)*1024) = tile rows
    // [c*16, c*16+16). lane l covers row c*16 + l/4, cols (l%4)*8 .. +8.
    const int srow = lane >> 2;
    const int scol = (lane & 3) * 8;
    const unsigned short* ga0 = A + (size_t)(m0 + wave * 16 + srow) * K + scol;
    const unsigned short* ga1 = A + (size_t)(m0 + (wave + 4) * 16 + srow) * K + scol;
    const unsigned short* gb0 = W + (size_t)(n0 + wave * 16 + srow) * K + scol;
    const unsigned short* gb1 = W + (size_t)(n0 + (wave + 4) * 16 + srow) * K + scol;
    unsigned short* lA0 = &As[wave * 512];
    unsigned short* lA1 = &As[(wave + 4) * 512];
    unsigned short* lB0 = &Bs[wave * 512];
    unsigned short* lB1 = &Bs[(wave + 4) * 512];

    // compute-side coords: wave quadrant + MFMA lane mapping
    const int wr = (wave >> 1) * 64;
    const int wc = (wave & 1) * 64;
    const int lq = lane >> 4;   // quad 0..3
    const int lm = lane & 15;

    f32x4 acc[4][4];
    #pragma unroll
    for (int i = 0; i < 4; ++i)
        #pragma unroll
        for (int j = 0; j < 4; ++j) acc[i][j] = 0.f;

    for (int k0 = 0; k0 < K; k0 += BK) {
        async_load16(ga0, lA0);
        async_load16(ga1, lA1);
        async_load16(gb0, lB0);
        async_load16(gb1, lB1);
        ga0 += BK; ga1 += BK; gb0 += BK; gb1 += BK;
        __syncthreads();   // drains vmcnt(0): LDS tiles visible

        bf16x8 af[4], bfr[4];
        #pragma unroll
        for (int i = 0; i < 4; ++i)
            af[i] = *(const bf16x8*)&As[(wr + i * 16 + lm) * BK + lq * 8];
        #pragma unroll
        for (int j = 0; j < 4; ++j)
            bfr[j] = *(const bf16x8*)&Bs[(wc + j * 16 + lm) * BK + lq * 8];

        #pragma unroll
        for (int i = 0; i < 4; ++i)
            #pragma unroll
            for (int j = 0; j < 4; ++j)
                acc[i][j] = __builtin_amdgcn_mfma_f32_16x16x32_bf16(
                    af[i], bfr[j], acc[i][j], 0, 0, 0);

        __syncthreads();   // protect LDS from next iteration's staging
    }

    // epilogue: C/D mapping col=lane&15, row=(lane>>4)*4+reg  [m89-verified]
    #pragma unroll
    for (int i = 0; i < 4; ++i) {
        #pragma unroll
        for (int j = 0; j < 4; ++j) {
            const int col = n0 + wc + j * 16 + lm;
            float bv = 0.f;
            if constexpr (HAS_BIAS) bv = b2f_raw(bias[col]);
            #pragma unroll
            for (int r = 0; r < 4; ++r) {
                const int row = m0 + wr + i * 16 + lq * 4 + r;
                const float v = acc[i][j][r] + bv;
                if constexpr (OBF)
                    ((__hip_bfloat16*)out)[(size_t)row * N + col] = __float2bfloat16(v);
                else
                    ((float*)out)[(size_t)row * N + col] = v;
            }
        }
    }
}

__global__ __launch_bounds__(256)
void gemm1_kernel(const unsigned short* __restrict__ xb,
                  const unsigned short* __restrict__ qkwb,
                  unsigned short* __restrict__ qk) {
    mfma_gemm_body<true, false>(xb, qkwb, nullptr, qk, B_ * N_, 2 * C_, C_);
}

__global__ __launch_bounds__(256)
void gemm2_kernel(const int* __restrict__ flag,
                  const unsigned short* __restrict__ attn,
                  const unsigned short* __restrict__ pwb,
                  const unsigned short* __restrict__ pbb,
                  void* __restrict__ out) {
    if (*flag) mfma_gemm_body<true, true>(attn, pwb, pbb, out, B_ * N_, C_, C_);
    else       mfma_gemm_body<false, true>(attn, pwb, pbb, out, B_ * N_, C_, C_);
}

// ---------------------------------------------------------------------------
// gen_weights: we_b[b,h,d,e] = sum_r x[b, idx[r], h*64+d] * we[h,r,e]
// idx[r] = (r*(N-1))/(R-1) exactly (trunc linspace). All inputs bf16 copies.
// ---------------------------------------------------------------------------
__global__ __launch_bounds__(256)
void genw_kernel(const unsigned short* __restrict__ xb,
                 const unsigned short* __restrict__ web_in,
                 const unsigned short* __restrict__ wrb_in,
                 float* __restrict__ web, float* __restrict__ wrb) {
    const int bh = blockIdx.x;
    const int b  = bh / H_;
    const int h  = bh % H_;
    for (int o = threadIdx.x; o < HD * LR; o += blockDim.x) {
        const int d = o / LR;
        const int e = o % LR;
        float acce = 0.f, accr = 0.f;
        for (int r = 0; r < RS; ++r) {
            const int ir = (r * (N_ - 1)) / (RS - 1);
            const float xv = b2f_raw(xb[((size_t)b * N_ + ir) * C_ + h * HD + d]);
            acce += xv * b2f_raw(web_in[((size_t)h * RS + r) * LR + e]);
            accr += xv * b2f_raw(wrb_in[((size_t)h * RS + r) * LR + e]);
        }
        web[(size_t)bh * HD * LR + o] = acce;
        wrb[(size_t)bh * HD * LR + o] = accr;
    }
}

// ---------------------------------------------------------------------------
// Fused per-(b,h,n): l2norm(q), l2norm(k) -> lr-scores -> cw projection.
// 256 threads = 4 waves; each wave handles one (bh,n); lane = head-dim idx.
// ---------------------------------------------------------------------------
__global__ __launch_bounds__(256)
void score_attn_kernel(const unsigned short* __restrict__ qk,
                       const float* __restrict__ web,
                       const float* __restrict__ wrb,
                       const unsigned short* __restrict__ cwwb,
                       const unsigned short* __restrict__ cwbb,
                       unsigned short* __restrict__ attn) {
    const int wave = threadIdx.x >> 6;
    const int lane = threadIdx.x & 63;
    const int gid  = blockIdx.x * 4 + wave;   // bh * N_ + n
    const int n    = gid % N_;
    const int bh   = gid / N_;
    const int h    = bh % H_;
    const int b    = bh / H_;

    const size_t rowq = ((size_t)(b * N_ + n)) * (2 * C_) + h * HD + lane;
    const float qv = b2f_raw(qk[rowq]);
    const float kv = b2f_raw(qk[rowq + C_]);

    float sq = qv * qv, sk = kv * kv;
    #pragma unroll
    for (int m = 1; m < 64; m <<= 1) {
        sq += __shfl_xor(sq, m, 64);
        sk += __shfl_xor(sk, m, 64);
    }
    const float qn = qv / fmaxf(sqrtf(sq), 1e-12f);
    const float kn = kv / fmaxf(sqrtf(sk), 1e-12f);

    __shared__ float qs[4][HD], ks[4][HD], sc[4][2 * LR];
    qs[wave][lane] = qn;
    ks[wave][lane] = kn;
    __syncthreads();

    const float* wb = web + (size_t)bh * HD * LR;
    const float* rb = wrb + (size_t)bh * HD * LR;
    if (lane < LR) {
        float s = 0.f;
        #pragma unroll 8
        for (int d = 0; d < HD; ++d) s += qs[wave][d] * wb[d * LR + lane];
        sc[wave][lane] = s;
    } else if (lane >= 32 && lane < 32 + LR) {
        const int e = lane - 32;
        float s = 0.f;
        #pragma unroll 8
        for (int d = 0; d < HD; ++d) s += ks[wave][d] * rb[d * LR + e];
        sc[wave][LR + e] = s;
    }
    __syncthreads();

    float a = b2f_raw(cwbb[lane]);
    #pragma unroll
    for (int e = 0; e < 2 * LR; ++e)
        a += sc[wave][e] * b2f_raw(cwwb[lane * 2 * LR + e]);

    attn[((size_t)(b * N_ + n)) * C_ + h * HD + lane] = f2b(a);
}

// ---------------------------------------------------------------------------
extern "C" void kernel_launch(void* const* d_in, const int* in_sizes, int n_in,
                              void* d_out, int out_size, void* d_ws, size_t ws_size,
                              hipStream_t stream) {
    (void)in_sizes; (void)n_in; (void)out_size; (void)ws_size;

    char* ws = (char*)d_ws;
    size_t off = 0;
    auto alloc = [&](size_t bytes) {
        char* p = ws + off;
        off += (bytes + 255) & ~(size_t)255;
        return p;
    };

    int* flag = (int*)alloc(16);
    // bf16 copies of inputs
    unsigned short* xb    = (unsigned short*)alloc((size_t)B_ * N_ * C_ * 2);        // 16.8 MB
    unsigned short* qkwb  = (unsigned short*)alloc((size_t)2 * C_ * C_ * 2);         // 4.2 MB
    unsigned short* pwb   = (unsigned short*)alloc((size_t)C_ * C_ * 2);             // 2.1 MB
    unsigned short* pbb   = (unsigned short*)alloc((size_t)C_ * 2);
    unsigned short* web_i = (unsigned short*)alloc((size_t)H_ * RS * LR * 2);
    unsigned short* wrb_i = (unsigned short*)alloc((size_t)H_ * RS * LR * 2);
    unsigned short* cwwb  = (unsigned short*)alloc((size_t)HD * 2 * LR * 2);
    unsigned short* cwbb  = (unsigned short*)alloc((size_t)HD * 2);
    // intermediates
    unsigned short* qk    = (unsigned short*)alloc((size_t)B_ * N_ * 2 * C_ * 2);    // 32 MB
    unsigned short* attn  = (unsigned short*)alloc((size_t)B_ * N_ * C_ * 2);        // 16 MB
    float* web            = (float*)alloc((size_t)B_ * H_ * HD * LR * 4);
    float* wrb            = (float*)alloc((size_t)B_ * H_ * HD * LR * 4);

    const int M = B_ * N_;  // 8192

    // 0) dtype detection
    detect_kernel<<<1, 256, 0, stream>>>((const unsigned int*)d_in[0], flag);

    // 1) convert all inputs to bf16 copies
    CvtArgs ca;
    ca.src[0] = d_in[0]; ca.dst[0] = xb;    ca.size[0] = B_ * N_ * C_;
    ca.src[1] = d_in[1]; ca.dst[1] = qkwb;  ca.size[1] = 2 * C_ * C_;
    ca.src[2] = d_in[2]; ca.dst[2] = pwb;   ca.size[2] = C_ * C_;
    ca.src[3] = d_in[3]; ca.dst[3] = pbb;   ca.size[3] = C_;
    ca.src[4] = d_in[4]; ca.dst[4] = web_i; ca.size[4] = H_ * RS * LR;
    ca.src[5] = d_in[5]; ca.dst[5] = wrb_i; ca.size[5] = H_ * RS * LR;
    ca.src[6] = d_in[6]; ca.dst[6] = cwwb;  ca.size[6] = HD * 2 * LR;
    ca.src[7] = d_in[7]; ca.dst[7] = cwbb;  ca.size[7] = HD;
    convert_kernel<<<dim3(2048, 8), 256, 0, stream>>>(flag, ca);

    // 2) qk projection: [M, 2C] = x @ qk_w^T  (MFMA)
    gemm1_kernel<<<dim3((2 * C_) / 128, M / 128), 256, 0, stream>>>(xb, qkwb, qk);

    // 3) low-rank weight generation (tiny)
    genw_kernel<<<B_ * H_, 256, 0, stream>>>(xb, web_i, wrb_i, web, wrb);

    // 4) fused normalize + scores + cw projection -> attn [B,N,C]
    score_attn_kernel<<<(B_ * H_ * N_) / 4, 256, 0, stream>>>(qk, web, wrb, cwwb, cwbb, attn);

    // 5) output projection: out = attn @ proj_w^T + proj_b  (MFMA)
    gemm2_kernel<<<dim3(C_ / 128, M / 128), 256, 0, stream>>>(flag, attn, pwb, pbb, d_out);
}

// Round 4
// 268.696 us; speedup vs baseline: 3.9183x; 1.4755x over previous
//
#include <hip/hip_runtime.h>
#include <hip/hip_bf16.h>

// Problem shapes (fixed by setup_inputs)
constexpr int B_  = 4;
constexpr int N_  = 2048;
constexpr int C_  = 1024;
constexpr int H_  = 16;
constexpr int HD  = 64;    // head dim
constexpr int LR  = 20;    // low rank
constexpr int RS  = 200;   // subsample length R

typedef __attribute__((ext_vector_type(8))) short bf16x8;
typedef __attribute__((ext_vector_type(4))) float f32x4;

__device__ __forceinline__ float b2f_raw(unsigned short u) {
    union { unsigned int i; float f; } v;
    v.i = ((unsigned int)u) << 16;
    return v.f;
}
__device__ __forceinline__ unsigned short f2b(float f) {
    __hip_bfloat16 h = __float2bfloat16(f);
    return *(unsigned short*)&h;
}

// async 16B global->LDS (wave-uniform LDS base; HW scatters lane i at +16*i)
__device__ __forceinline__ void async_load16(const unsigned short* g, unsigned short* l) {
    __builtin_amdgcn_global_load_lds(
        (const __attribute__((address_space(1))) unsigned int*)(const void*)g,
        (__attribute__((address_space(3))) unsigned int*)(void*)l,
        16, 0, 0);
}

// ---------------------------------------------------------------------------
// dtype detection: low 16 bits of fp32 words are uniform mantissa bits; of
// packed bf16 pairs they are a real bf16 sample (exponent in [103,140]).
// ---------------------------------------------------------------------------
__global__ __launch_bounds__(256)
void detect_kernel(const unsigned int* __restrict__ x, int* __restrict__ flag) {
    const int t = threadIdx.x;
    int cnt = 0;
    for (int i = t; i < 1024; i += 256) {
        const unsigned int w = x[i];
        const unsigned int e = (w >> 7) & 0xFFu;
        cnt += (e >= 103u && e <= 140u) ? 1 : 0;
    }
    __shared__ int s[256];
    s[t] = cnt;
    __syncthreads();
    for (int off = 128; off > 0; off >>= 1) {
        if (t < off) s[t] += s[t + off];
        __syncthreads();
    }
    if (t == 0) *flag = (s[0] > 512) ? 1 : 0;  // 1 = bf16 inputs, 0 = fp32
}

// ---------------------------------------------------------------------------
// Convert all 8 inputs to bf16 copies in ws. blockIdx.y selects buffer.
// ---------------------------------------------------------------------------
struct CvtArgs {
    const void* src[8];
    unsigned short* dst[8];
    int size[8];
};

__global__ __launch_bounds__(256)
void convert_kernel(const int* __restrict__ flag, CvtArgs args) {
    const int buf = blockIdx.y;
    const int n4 = args.size[buf] >> 2;
    const int stride = gridDim.x * blockDim.x;
    const bool isbf = (*flag != 0);
    for (int i = blockIdx.x * blockDim.x + threadIdx.x; i < n4; i += stride) {
        ushort4 o;
        if (isbf) {
            o = ((const ushort4*)args.src[buf])[i];
        } else {
            const float4 v = ((const float4*)args.src[buf])[i];
            o.x = f2b(v.x); o.y = f2b(v.y); o.z = f2b(v.z); o.w = f2b(v.w);
        }
        ((ushort4*)args.dst[buf])[i] = o;
    }
}

// ---------------------------------------------------------------------------
// MFMA GEMM (NT): out[m,n] = sum_k A[m,k]*W[n,k] (+bias[n]). 128x128 tile,
// BK=32, 256 thr (4 waves), each wave a 64x64 quadrant of 4x4 16x16x32 MFMAs.
// LDS tiles linear [row][k] (global_load_lds constraint: no padding).
// ---------------------------------------------------------------------------
template <bool OBF, bool HAS_BIAS>
__device__ void mfma_gemm_body(const unsigned short* __restrict__ A,
                               const unsigned short* __restrict__ W,
                               const unsigned short* __restrict__ bias,
                               void* __restrict__ out,
                               int M, int N, int K) {
    constexpr int BM = 128, BN = 128, BK = 32;
    __shared__ __align__(16) unsigned short As[BM * BK];  // 8 KB
    __shared__ __align__(16) unsigned short Bs[BN * BK];  // 8 KB

    const int t    = threadIdx.x;
    const int wave = t >> 6;
    const int lane = t & 63;
    const int m0   = blockIdx.y * BM;
    const int n0   = blockIdx.x * BN;

    const int srow = lane >> 2;
    const int scol = (lane & 3) * 8;
    const unsigned short* ga0 = A + (size_t)(m0 + wave * 16 + srow) * K + scol;
    const unsigned short* ga1 = A + (size_t)(m0 + (wave + 4) * 16 + srow) * K + scol;
    const unsigned short* gb0 = W + (size_t)(n0 + wave * 16 + srow) * K + scol;
    const unsigned short* gb1 = W + (size_t)(n0 + (wave + 4) * 16 + srow) * K + scol;
    unsigned short* lA0 = &As[wave * 512];
    unsigned short* lA1 = &As[(wave + 4) * 512];
    unsigned short* lB0 = &Bs[wave * 512];
    unsigned short* lB1 = &Bs[(wave + 4) * 512];

    const int wr = (wave >> 1) * 64;
    const int wc = (wave & 1) * 64;
    const int lq = lane >> 4;
    const int lm = lane & 15;

    f32x4 acc[4][4];
    #pragma unroll
    for (int i = 0; i < 4; ++i)
        #pragma unroll
        for (int j = 0; j < 4; ++j) acc[i][j] = 0.f;

    for (int k0 = 0; k0 < K; k0 += BK) {
        async_load16(ga0, lA0);
        async_load16(ga1, lA1);
        async_load16(gb0, lB0);
        async_load16(gb1, lB1);
        ga0 += BK; ga1 += BK; gb0 += BK; gb1 += BK;
        __syncthreads();

        bf16x8 af[4], bfr[4];
        #pragma unroll
        for (int i = 0; i < 4; ++i)
            af[i] = *(const bf16x8*)&As[(wr + i * 16 + lm) * BK + lq * 8];
        #pragma unroll
        for (int j = 0; j < 4; ++j)
            bfr[j] = *(const bf16x8*)&Bs[(wc + j * 16 + lm) * BK + lq * 8];

        #pragma unroll
        for (int i = 0; i < 4; ++i)
            #pragma unroll
            for (int j = 0; j < 4; ++j)
                acc[i][j] = __builtin_amdgcn_mfma_f32_16x16x32_bf16(
                    af[i], bfr[j], acc[i][j], 0, 0, 0);

        __syncthreads();
    }

    #pragma unroll
    for (int i = 0; i < 4; ++i) {
        #pragma unroll
        for (int j = 0; j < 4; ++j) {
            const int col = n0 + wc + j * 16 + lm;
            float bv = 0.f;
            if constexpr (HAS_BIAS) bv = b2f_raw(bias[col]);
            #pragma unroll
            for (int r = 0; r < 4; ++r) {
                const int row = m0 + wr + i * 16 + lq * 4 + r;
                const float v = acc[i][j][r] + bv;
                if constexpr (OBF)
                    ((__hip_bfloat16*)out)[(size_t)row * N + col] = __float2bfloat16(v);
                else
                    ((float*)out)[(size_t)row * N + col] = v;
            }
        }
    }
}

__global__ __launch_bounds__(256)
void gemm1_kernel(const unsigned short* __restrict__ xb,
                  const unsigned short* __restrict__ qkwb,
                  unsigned short* __restrict__ qk) {
    mfma_gemm_body<true, false>(xb, qkwb, nullptr, qk, B_ * N_, 2 * C_, C_);
}

__global__ __launch_bounds__(256)
void gemm2_kernel(const int* __restrict__ flag,
                  const unsigned short* __restrict__ attn,
                  const unsigned short* __restrict__ pwb,
                  const unsigned short* __restrict__ pbb,
                  void* __restrict__ out) {
    if (*flag) mfma_gemm_body<true, true>(attn, pwb, pbb, out, B_ * N_, C_, C_);
    else       mfma_gemm_body<false, true>(attn, pwb, pbb, out, B_ * N_, C_, C_);
}

// ---------------------------------------------------------------------------
// gen_weights + collapse: per (b,h)
//   we_b[din][e] = sum_r x[b, idx[r], h*64+din] * we[h,r,e]   (fp32, LDS)
//   We2T[dout][din] = sum_e we_b[din][e] * cw_w[dout][e]       -> bf16
//   Wr2T[dout][din] = sum_e wr_b[din][e] * cw_w[dout][20+e]    -> bf16
// idx[r] = (r*(N-1))/(R-1) exactly (trunc linspace).
// ---------------------------------------------------------------------------
__global__ __launch_bounds__(256)
void genw_kernel(const unsigned short* __restrict__ xb,
                 const unsigned short* __restrict__ we_in,
                 const unsigned short* __restrict__ wr_in,
                 const unsigned short* __restrict__ cwwb,
                 unsigned short* __restrict__ we2t,
                 unsigned short* __restrict__ wr2t) {
    __shared__ float webs[HD * LR], wrbs[HD * LR];
    const int bh = blockIdx.x;
    const int b  = bh / H_;
    const int h  = bh % H_;

    for (int o = threadIdx.x; o < HD * LR; o += 256) {
        const int d = o / LR;
        const int e = o % LR;
        float acce = 0.f, accr = 0.f;
        for (int r = 0; r < RS; ++r) {
            const int ir = (r * (N_ - 1)) / (RS - 1);
            const float xv = b2f_raw(xb[((size_t)b * N_ + ir) * C_ + h * HD + d]);
            acce += xv * b2f_raw(we_in[((size_t)h * RS + r) * LR + e]);
            accr += xv * b2f_raw(wr_in[((size_t)h * RS + r) * LR + e]);
        }
        webs[o] = acce;
        wrbs[o] = accr;
    }
    __syncthreads();

    for (int o = threadIdx.x; o < HD * HD; o += 256) {
        const int dout = o >> 6;
        const int din  = o & 63;
        float sq = 0.f, sk = 0.f;
        #pragma unroll
        for (int e = 0; e < LR; ++e) {
            sq += webs[din * LR + e] * b2f_raw(cwwb[dout * 2 * LR + e]);
            sk += wrbs[din * LR + e] * b2f_raw(cwwb[dout * 2 * LR + LR + e]);
        }
        we2t[(size_t)bh * HD * HD + o] = f2b(sq);
        wr2t[(size_t)bh * HD * HD + o] = f2b(sk);
    }
}

// ---------------------------------------------------------------------------
// score+attn as MFMA: per (b,h):
//   attn = diag(1/|q|) Q We2 + diag(1/|k|) K Wr2 + cw_b
// One wave per 32 rows; A-frags loaded straight from global (64B row segs),
// row norms via 2x shfl_xor; separate Q/K accumulators scaled in epilogue.
// No LDS, no barriers.
// ---------------------------------------------------------------------------
__global__ __launch_bounds__(256)
void score_attn_kernel(const unsigned short* __restrict__ qk,
                       const unsigned short* __restrict__ we2t,
                       const unsigned short* __restrict__ wr2t,
                       const unsigned short* __restrict__ cwbb,
                       unsigned short* __restrict__ attn) {
    const int wave = threadIdx.x >> 6;
    const int lane = threadIdx.x & 63;
    const int wg   = blockIdx.x * 4 + wave;   // global wave id
    const int bh   = wg >> 6;                 // 64 waves per (b,h)
    const int n0   = (wg & 63) * 32;          // row start within (b,h)
    const int b    = bh >> 4;
    const int h    = bh & 15;
    const int lq   = lane >> 4;
    const int lm   = lane & 15;

    // B fragments (We2T/Wr2T are [bh][dout][din], din contiguous)
    bf16x8 bq[2][4], bk[2][4];                // [kstep][coltile]
    {
        const unsigned short* wq = we2t + (size_t)bh * HD * HD;
        const unsigned short* wk = wr2t + (size_t)bh * HD * HD;
        #pragma unroll
        for (int t2 = 0; t2 < 2; ++t2)
            #pragma unroll
            for (int j = 0; j < 4; ++j) {
                const int dout = j * 16 + lm;
                bq[t2][j] = *(const bf16x8*)&wq[dout * HD + t2 * 32 + lq * 8];
                bk[t2][j] = *(const bf16x8*)&wk[dout * HD + t2 * 32 + lq * 8];
            }
    }

    f32x4 accQ[2][4], accK[2][4];
    #pragma unroll
    for (int i = 0; i < 2; ++i)
        #pragma unroll
        for (int j = 0; j < 4; ++j) { accQ[i][j] = 0.f; accK[i][j] = 0.f; }

    float invq[2], invk[2];

    #pragma unroll
    for (int rt = 0; rt < 2; ++rt) {
        const int row = n0 + rt * 16 + lm;
        const size_t base = ((size_t)(b * N_ + row)) * (2 * C_) + h * HD;
        bf16x8 aq[2], ak[2];
        aq[0] = *(const bf16x8*)&qk[base + lq * 8];
        aq[1] = *(const bf16x8*)&qk[base + 32 + lq * 8];
        ak[0] = *(const bf16x8*)&qk[base + C_ + lq * 8];
        ak[1] = *(const bf16x8*)&qk[base + C_ + 32 + lq * 8];

        float sq = 0.f, sk = 0.f;
        #pragma unroll
        for (int t2 = 0; t2 < 2; ++t2)
            #pragma unroll
            for (int j = 0; j < 8; ++j) {
                const float vq = b2f_raw((unsigned short)aq[t2][j]);
                const float vk = b2f_raw((unsigned short)ak[t2][j]);
                sq += vq * vq;
                sk += vk * vk;
            }
        sq += __shfl_xor(sq, 16, 64);
        sq += __shfl_xor(sq, 32, 64);
        sk += __shfl_xor(sk, 16, 64);
        sk += __shfl_xor(sk, 32, 64);
        invq[rt] = 1.f / fmaxf(sqrtf(sq), 1e-12f);
        invk[rt] = 1.f / fmaxf(sqrtf(sk), 1e-12f);

        #pragma unroll
        for (int t2 = 0; t2 < 2; ++t2)
            #pragma unroll
            for (int j = 0; j < 4; ++j) {
                accQ[rt][j] = __builtin_amdgcn_mfma_f32_16x16x32_bf16(
                    aq[t2], bq[t2][j], accQ[rt][j], 0, 0, 0);
                accK[rt][j] = __builtin_amdgcn_mfma_f32_16x16x32_bf16(
                    ak[t2], bk[t2][j], accK[rt][j], 0, 0, 0);
            }
    }

    // epilogue: C-layout row = lq*4+r, col = j*16+lm
    #pragma unroll
    for (int rt = 0; rt < 2; ++rt) {
        float iq[4], ik[4];
        #pragma unroll
        for (int r = 0; r < 4; ++r) {
            iq[r] = __shfl(invq[rt], lq * 4 + r, 64);
            ik[r] = __shfl(invk[rt], lq * 4 + r, 64);
        }
        #pragma unroll
        for (int j = 0; j < 4; ++j) {
            const float bv = b2f_raw(cwbb[j * 16 + lm]);
            #pragma unroll
            for (int r = 0; r < 4; ++r) {
                const int row = n0 + rt * 16 + lq * 4 + r;
                const float v = accQ[rt][j][r] * iq[r] + accK[rt][j][r] * ik[r] + bv;
                attn[((size_t)(b * N_ + row)) * C_ + h * HD + j * 16 + lm] = f2b(v);
            }
        }
    }
}

// ---------------------------------------------------------------------------
extern "C" void kernel_launch(void* const* d_in, const int* in_sizes, int n_in,
                              void* d_out, int out_size, void* d_ws, size_t ws_size,
                              hipStream_t stream) {
    (void)in_sizes; (void)n_in; (void)out_size; (void)ws_size;

    char* ws = (char*)d_ws;
    size_t off = 0;
    auto alloc = [&](size_t bytes) {
        char* p = ws + off;
        off += (bytes + 255) & ~(size_t)255;
        return p;
    };

    int* flag = (int*)alloc(16);
    unsigned short* xb    = (unsigned short*)alloc((size_t)B_ * N_ * C_ * 2);
    unsigned short* qkwb  = (unsigned short*)alloc((size_t)2 * C_ * C_ * 2);
    unsigned short* pwb   = (unsigned short*)alloc((size_t)C_ * C_ * 2);
    unsigned short* pbb   = (unsigned short*)alloc((size_t)C_ * 2);
    unsigned short* we_i  = (unsigned short*)alloc((size_t)H_ * RS * LR * 2);
    unsigned short* wr_i  = (unsigned short*)alloc((size_t)H_ * RS * LR * 2);
    unsigned short* cwwb  = (unsigned short*)alloc((size_t)HD * 2 * LR * 2);
    unsigned short* cwbb  = (unsigned short*)alloc((size_t)HD * 2);
    unsigned short* qk    = (unsigned short*)alloc((size_t)B_ * N_ * 2 * C_ * 2);
    unsigned short* attn  = (unsigned short*)alloc((size_t)B_ * N_ * C_ * 2);
    unsigned short* we2t  = (unsigned short*)alloc((size_t)B_ * H_ * HD * HD * 2);
    unsigned short* wr2t  = (unsigned short*)alloc((size_t)B_ * H_ * HD * HD * 2);

    const int M = B_ * N_;  // 8192

    // 0) dtype detection
    detect_kernel<<<1, 256, 0, stream>>>((const unsigned int*)d_in[0], flag);

    // 1) convert all inputs to bf16 copies
    CvtArgs ca;
    ca.src[0] = d_in[0]; ca.dst[0] = xb;   ca.size[0] = B_ * N_ * C_;
    ca.src[1] = d_in[1]; ca.dst[1] = qkwb; ca.size[1] = 2 * C_ * C_;
    ca.src[2] = d_in[2]; ca.dst[2] = pwb;  ca.size[2] = C_ * C_;
    ca.src[3] = d_in[3]; ca.dst[3] = pbb;  ca.size[3] = C_;
    ca.src[4] = d_in[4]; ca.dst[4] = we_i; ca.size[4] = H_ * RS * LR;
    ca.src[5] = d_in[5]; ca.dst[5] = wr_i; ca.size[5] = H_ * RS * LR;
    ca.src[6] = d_in[6]; ca.dst[6] = cwwb; ca.size[6] = HD * 2 * LR;
    ca.src[7] = d_in[7]; ca.dst[7] = cwbb; ca.size[7] = HD;
    convert_kernel<<<dim3(2048, 8), 256, 0, stream>>>(flag, ca);

    // 2) qk projection: [M, 2C] = x @ qk_w^T  (MFMA)
    gemm1_kernel<<<dim3((2 * C_) / 128, M / 128), 256, 0, stream>>>(xb, qkwb, qk);

    // 3) low-rank weight generation + collapse to We2T/Wr2T
    genw_kernel<<<B_ * H_, 256, 0, stream>>>(xb, we_i, wr_i, cwwb, we2t, wr2t);

    // 4) score+attn as per-head MFMA GEMMs with epilogue row-norm
    score_attn_kernel<<<(B_ * H_ * N_ / 32) / 4, 256, 0, stream>>>(
        qk, we2t, wr2t, cwbb, attn);

    // 5) output projection: out = attn @ proj_w^T + proj_b  (MFMA)
    gemm2_kernel<<<dim3(C_ / 128, M / 128), 256, 0, stream>>>(flag, attn, pwb, pbb, d_out);
}

// Round 6
// 229.618 us; speedup vs baseline: 4.5851x; 1.1702x over previous
//
#include <hip/hip_runtime.h>
#include <hip/hip_bf16.h>

// Problem shapes (fixed by setup_inputs)
constexpr int B_  = 4;
constexpr int N_  = 2048;
constexpr int C_  = 1024;
constexpr int H_  = 16;
constexpr int HD  = 64;    // head dim
constexpr int LR  = 20;    // low rank
constexpr int RS  = 200;   // subsample length R
constexpr int RP  = 224;   // RS padded to multiple of 32 (zero-filled)

typedef __attribute__((ext_vector_type(8))) short bf16x8;
typedef __attribute__((ext_vector_type(4))) float f32x4;

__device__ __forceinline__ float b2f_raw(unsigned short u) {
    union { unsigned int i; float f; } v;
    v.i = ((unsigned int)u) << 16;
    return v.f;
}
__device__ __forceinline__ unsigned short f2b(float f) {
    __hip_bfloat16 h = __float2bfloat16(f);
    return *(unsigned short*)&h;
}

// async 16B global->LDS (wave-uniform LDS base; HW scatters lane i at +16*i)
__device__ __forceinline__ void async_load16(const unsigned short* g, unsigned short* l) {
    __builtin_amdgcn_global_load_lds(
        (const __attribute__((address_space(1))) unsigned int*)(const void*)g,
        (__attribute__((address_space(3))) unsigned int*)(void*)l,
        16, 0, 0);
}

// ---------------------------------------------------------------------------
// dtype detection: low 16 bits of fp32 words are uniform mantissa bits; of
// packed bf16 pairs they are a real bf16 sample (exponent in [103,140]).
// ---------------------------------------------------------------------------
__global__ __launch_bounds__(256)
void detect_kernel(const unsigned int* __restrict__ x, int* __restrict__ flag) {
    const int t = threadIdx.x;
    int cnt = 0;
    for (int i = t; i < 1024; i += 256) {
        const unsigned int w = x[i];
        const unsigned int e = (w >> 7) & 0xFFu;
        cnt += (e >= 103u && e <= 140u) ? 1 : 0;
    }
    __shared__ int s[256];
    s[t] = cnt;
    __syncthreads();
    for (int off = 128; off > 0; off >>= 1) {
        if (t < off) s[t] += s[t + off];
        __syncthreads();
    }
    if (t == 0) *flag = (s[0] > 512) ? 1 : 0;  // 1 = bf16 inputs, 0 = fp32
}

// ---------------------------------------------------------------------------
// Convert all 8 inputs to bf16 copies in ws. blockIdx.y selects buffer.
// ---------------------------------------------------------------------------
struct CvtArgs {
    const void* src[8];
    unsigned short* dst[8];
    int size[8];
};

__global__ __launch_bounds__(256)
void convert_kernel(const int* __restrict__ flag, CvtArgs args) {
    const int buf = blockIdx.y;
    const int n4 = args.size[buf] >> 2;
    const int stride = gridDim.x * blockDim.x;
    const bool isbf = (*flag != 0);
    for (int i = blockIdx.x * blockDim.x + threadIdx.x; i < n4; i += stride) {
        ushort4 o;
        if (isbf) {
            o = ((const ushort4*)args.src[buf])[i];
        } else {
            const float4 v = ((const float4*)args.src[buf])[i];
            o.x = f2b(v.x); o.y = f2b(v.y); o.z = f2b(v.z); o.w = f2b(v.w);
        }
        ((ushort4*)args.dst[buf])[i] = o;
    }
}

// ---------------------------------------------------------------------------
// MFMA GEMM (NT): out[m,n] = sum_k A[m,k]*W[n,k] (+bias[n]). 128x128 tile,
// BK=32, 256 thr (4 waves), each wave a 64x64 quadrant of 4x4 16x16x32 MFMAs.
// LDS tiles linear [row][k] (global_load_lds constraint: no padding).
// ---------------------------------------------------------------------------
template <bool OBF, bool HAS_BIAS>
__device__ void mfma_gemm_body(const unsigned short* __restrict__ A,
                               const unsigned short* __restrict__ W,
                               const unsigned short* __restrict__ bias,
                               void* __restrict__ out,
                               int M, int N, int K) {
    constexpr int BM = 128, BN = 128, BK = 32;
    __shared__ __align__(16) unsigned short As[BM * BK];  // 8 KB
    __shared__ __align__(16) unsigned short Bs[BN * BK];  // 8 KB

    const int t    = threadIdx.x;
    const int wave = t >> 6;
    const int lane = t & 63;
    const int m0   = blockIdx.y * BM;
    const int n0   = blockIdx.x * BN;

    const int srow = lane >> 2;
    const int scol = (lane & 3) * 8;
    const unsigned short* ga0 = A + (size_t)(m0 + wave * 16 + srow) * K + scol;
    const unsigned short* ga1 = A + (size_t)(m0 + (wave + 4) * 16 + srow) * K + scol;
    const unsigned short* gb0 = W + (size_t)(n0 + wave * 16 + srow) * K + scol;
    const unsigned short* gb1 = W + (size_t)(n0 + (wave + 4) * 16 + srow) * K + scol;
    unsigned short* lA0 = &As[wave * 512];
    unsigned short* lA1 = &As[(wave + 4) * 512];
    unsigned short* lB0 = &Bs[wave * 512];
    unsigned short* lB1 = &Bs[(wave + 4) * 512];

    const int wr = (wave >> 1) * 64;
    const int wc = (wave & 1) * 64;
    const int lq = lane >> 4;
    const int lm = lane & 15;

    f32x4 acc[4][4];
    #pragma unroll
    for (int i = 0; i < 4; ++i)
        #pragma unroll
        for (int j = 0; j < 4; ++j) acc[i][j] = 0.f;

    for (int k0 = 0; k0 < K; k0 += BK) {
        async_load16(ga0, lA0);
        async_load16(ga1, lA1);
        async_load16(gb0, lB0);
        async_load16(gb1, lB1);
        ga0 += BK; ga1 += BK; gb0 += BK; gb1 += BK;
        __syncthreads();

        bf16x8 af[4], bfr[4];
        #pragma unroll
        for (int i = 0; i < 4; ++i)
            af[i] = *(const bf16x8*)&As[(wr + i * 16 + lm) * BK + lq * 8];
        #pragma unroll
        for (int j = 0; j < 4; ++j)
            bfr[j] = *(const bf16x8*)&Bs[(wc + j * 16 + lm) * BK + lq * 8];

        #pragma unroll
        for (int i = 0; i < 4; ++i)
            #pragma unroll
            for (int j = 0; j < 4; ++j)
                acc[i][j] = __builtin_amdgcn_mfma_f32_16x16x32_bf16(
                    af[i], bfr[j], acc[i][j], 0, 0, 0);

        __syncthreads();
    }

    #pragma unroll
    for (int i = 0; i < 4; ++i) {
        #pragma unroll
        for (int j = 0; j < 4; ++j) {
            const int col = n0 + wc + j * 16 + lm;
            float bv = 0.f;
            if constexpr (HAS_BIAS) bv = b2f_raw(bias[col]);
            #pragma unroll
            for (int r = 0; r < 4; ++r) {
                const int row = m0 + wr + i * 16 + lq * 4 + r;
                const float v = acc[i][j][r] + bv;
                if constexpr (OBF)
                    ((__hip_bfloat16*)out)[(size_t)row * N + col] = __float2bfloat16(v);
                else
                    ((float*)out)[(size_t)row * N + col] = v;
            }
        }
    }
}

__global__ __launch_bounds__(256)
void gemm1_kernel(const unsigned short* __restrict__ xb,
                  const unsigned short* __restrict__ qkwb,
                  unsigned short* __restrict__ qk) {
    mfma_gemm_body<true, false>(xb, qkwb, nullptr, qk, B_ * N_, 2 * C_, C_);
}

__global__ __launch_bounds__(256)
void gemm2_kernel(const int* __restrict__ flag,
                  const unsigned short* __restrict__ attn,
                  const unsigned short* __restrict__ pwb,
                  const unsigned short* __restrict__ pbb,
                  void* __restrict__ out) {
    if (*flag) mfma_gemm_body<true, true>(attn, pwb, pbb, out, B_ * N_, C_, C_);
    else       mfma_gemm_body<false, true>(attn, pwb, pbb, out, B_ * N_, C_, C_);
}

// ---------------------------------------------------------------------------
// Stage A0: wec[h][dout][r] = sum_e we[h,r,e]*cw_w[dout,e]        (x-indep!)
//           wrc[h][dout][r] = sum_e wr[h,r,e]*cw_w[dout,20+e]
// r padded to RP=224 with zeros. Flat grid over 16*64*224 outputs.
// ---------------------------------------------------------------------------
__global__ __launch_bounds__(256)
void wec_kernel(const unsigned short* __restrict__ we_in,
                const unsigned short* __restrict__ wr_in,
                const unsigned short* __restrict__ cwwb,
                unsigned short* __restrict__ wect,
                unsigned short* __restrict__ wrct) {
    const int o = blockIdx.x * 256 + threadIdx.x;
    if (o >= H_ * HD * RP) return;
    const int r    = o % RP;
    const int dout = (o / RP) % HD;
    const int h    = o / (RP * HD);
    float sq = 0.f, sk = 0.f;
    if (r < RS) {
        #pragma unroll
        for (int e = 0; e < LR; ++e) {
            const float cq = b2f_raw(cwwb[dout * 2 * LR + e]);
            const float ck = b2f_raw(cwwb[dout * 2 * LR + LR + e]);
            sq += b2f_raw(we_in[((size_t)h * RS + r) * LR + e]) * cq;
            sk += b2f_raw(wr_in[((size_t)h * RS + r) * LR + e]) * ck;
        }
    }
    wect[o] = f2b(sq);
    wrct[o] = f2b(sk);
}

// ---------------------------------------------------------------------------
// Stage A1: xh[bh][din][r] = x[b, idx[r], h*64+din], r in [0,224) (zero-pad).
// idx[r] = (r*(N-1))/(R-1) exactly (trunc linspace). Reads coalesced over din.
// ---------------------------------------------------------------------------
__global__ __launch_bounds__(256)
void gather_kernel(const unsigned short* __restrict__ xb,
                   unsigned short* __restrict__ xh) {
    const int bh = blockIdx.x;
    const int b  = bh >> 4;
    const int h  = bh & 15;
    for (int o = threadIdx.x; o < HD * RP; o += 256) {
        const int din = o & 63;     // consecutive threads -> coalesced read
        const int r   = o >> 6;
        unsigned short v = 0;
        if (r < RS) {
            const int ir = (r * (N_ - 1)) / (RS - 1);
            v = xb[((size_t)b * N_ + ir) * C_ + h * HD + din];
        }
        xh[(size_t)bh * HD * RP + (size_t)din * RP + r] = v;
    }
}

// ---------------------------------------------------------------------------
// Stage A2: We2T[bh][dout][din] = sum_r wec[h][dout][r] * xh[bh][din][r]
// Tiny NT MFMA GEMM, M=N=64, K=224. One wave per (bh, qk-sel, dout-half):
// 256 blocks x 64 threads; 2 rowtiles x 4 coltiles x 7 ksteps = 56 MFMAs.
// ---------------------------------------------------------------------------
__global__ __launch_bounds__(64)
void collapse_kernel(const unsigned short* __restrict__ xh,
                     const unsigned short* __restrict__ wect,
                     const unsigned short* __restrict__ wrct,
                     unsigned short* __restrict__ we2t,
                     unsigned short* __restrict__ wr2t) {
    const int blk = blockIdx.x;
    const int bh  = blk >> 2;
    const int qk  = (blk >> 1) & 1;
    const int dh  = blk & 1;          // dout half: rows [dh*32, dh*32+32)
    const int h   = bh & 15;
    const int lane = threadIdx.x;
    const int lq = lane >> 4;
    const int lm = lane & 15;

    const unsigned short* wsrc = (qk ? wrct : wect) + (size_t)h * HD * RP;
    const unsigned short* xsrc = xh + (size_t)bh * HD * RP;
    unsigned short* dst = (qk ? wr2t : we2t) + (size_t)bh * HD * HD;

    f32x4 acc[2][4];
    #pragma unroll
    for (int i = 0; i < 2; ++i)
        #pragma unroll
        for (int j = 0; j < 4; ++j) acc[i][j] = 0.f;

    for (int ks = 0; ks < RP / 32; ++ks) {
        bf16x8 a[2], bfr[4];
        #pragma unroll
        for (int rt = 0; rt < 2; ++rt)
            a[rt] = *(const bf16x8*)&wsrc[(size_t)(dh * 32 + rt * 16 + lm) * RP + ks * 32 + lq * 8];
        #pragma unroll
        for (int j = 0; j < 4; ++j)
            bfr[j] = *(const bf16x8*)&xsrc[(size_t)(j * 16 + lm) * RP + ks * 32 + lq * 8];
        #pragma unroll
        for (int rt = 0; rt < 2; ++rt)
            #pragma unroll
            for (int j = 0; j < 4; ++j)
                acc[rt][j] = __builtin_amdgcn_mfma_f32_16x16x32_bf16(
                    a[rt], bfr[j], acc[rt][j], 0, 0, 0);
    }

    // C-layout: col(din)=j*16+lm, row-in-tile=lq*4+r
    #pragma unroll
    for (int rt = 0; rt < 2; ++rt)
        #pragma unroll
        for (int j = 0; j < 4; ++j)
            #pragma unroll
            for (int r = 0; r < 4; ++r) {
                const int dout = dh * 32 + rt * 16 + lq * 4 + r;
                const int din  = j * 16 + lm;
                dst[dout * HD + din] = f2b(acc[rt][j][r]);
            }
}

// ---------------------------------------------------------------------------
// score+attn as MFMA: per (b,h): attn = diag(1/|q|) Q We2 + diag(1/|k|) K Wr2
// + cw_b. One wave per 32 rows; A-frags straight from global; row norms via
// shfl; separate Q/K accumulators scaled in epilogue. No LDS, no barriers.
// ---------------------------------------------------------------------------
__global__ __launch_bounds__(256)
void score_attn_kernel(const unsigned short* __restrict__ qk,
                       const unsigned short* __restrict__ we2t,
                       const unsigned short* __restrict__ wr2t,
                       const unsigned short* __restrict__ cwbb,
                       unsigned short* __restrict__ attn) {
    const int wave = threadIdx.x >> 6;
    const int lane = threadIdx.x & 63;
    const int wg   = blockIdx.x * 4 + wave;
    const int bh   = wg >> 6;
    const int n0   = (wg & 63) * 32;
    const int b    = bh >> 4;
    const int h    = bh & 15;
    const int lq   = lane >> 4;
    const int lm   = lane & 15;

    bf16x8 bq[2][4], bk[2][4];
    {
        const unsigned short* wq = we2t + (size_t)bh * HD * HD;
        const unsigned short* wk = wr2t + (size_t)bh * HD * HD;
        #pragma unroll
        for (int t2 = 0; t2 < 2; ++t2)
            #pragma unroll
            for (int j = 0; j < 4; ++j) {
                const int dout = j * 16 + lm;
                bq[t2][j] = *(const bf16x8*)&wq[dout * HD + t2 * 32 + lq * 8];
                bk[t2][j] = *(const bf16x8*)&wk[dout * HD + t2 * 32 + lq * 8];
            }
    }

    f32x4 accQ[2][4], accK[2][4];
    #pragma unroll
    for (int i = 0; i < 2; ++i)
        #pragma unroll
        for (int j = 0; j < 4; ++j) { accQ[i][j] = 0.f; accK[i][j] = 0.f; }

    float invq[2], invk[2];

    #pragma unroll
    for (int rt = 0; rt < 2; ++rt) {
        const int row = n0 + rt * 16 + lm;
        const size_t base = ((size_t)(b * N_ + row)) * (2 * C_) + h * HD;
        bf16x8 aq[2], ak[2];
        aq[0] = *(const bf16x8*)&qk[base + lq * 8];
        aq[1] = *(const bf16x8*)&qk[base + 32 + lq * 8];
        ak[0] = *(const bf16x8*)&qk[base + C_ + lq * 8];
        ak[1] = *(const bf16x8*)&qk[base + C_ + 32 + lq * 8];

        float sq = 0.f, sk = 0.f;
        #pragma unroll
        for (int t2 = 0; t2 < 2; ++t2)
            #pragma unroll
            for (int j = 0; j < 8; ++j) {
                const float vq = b2f_raw((unsigned short)aq[t2][j]);
                const float vk = b2f_raw((unsigned short)ak[t2][j]);
                sq += vq * vq;
                sk += vk * vk;
            }
        sq += __shfl_xor(sq, 16, 64);
        sq += __shfl_xor(sq, 32, 64);
        sk += __shfl_xor(sk, 16, 64);
        sk += __shfl_xor(sk, 32, 64);
        invq[rt] = 1.f / fmaxf(sqrtf(sq), 1e-12f);
        invk[rt] = 1.f / fmaxf(sqrtf(sk), 1e-12f);

        #pragma unroll
        for (int t2 = 0; t2 < 2; ++t2)
            #pragma unroll
            for (int j = 0; j < 4; ++j) {
                accQ[rt][j] = __builtin_amdgcn_mfma_f32_16x16x32_bf16(
                    aq[t2], bq[t2][j], accQ[rt][j], 0, 0, 0);
                accK[rt][j] = __builtin_amdgcn_mfma_f32_16x16x32_bf16(
                    ak[t2], bk[t2][j], accK[rt][j], 0, 0, 0);
            }
    }

    #pragma unroll
    for (int rt = 0; rt < 2; ++rt) {
        float iq[4], ik[4];
        #pragma unroll
        for (int r = 0; r < 4; ++r) {
            iq[r] = __shfl(invq[rt], lq * 4 + r, 64);
            ik[r] = __shfl(invk[rt], lq * 4 + r, 64);
        }
        #pragma unroll
        for (int j = 0; j < 4; ++j) {
            const float bv = b2f_raw(cwbb[j * 16 + lm]);
            #pragma unroll
            for (int r = 0; r < 4; ++r) {
                const int row = n0 + rt * 16 + lq * 4 + r;
                const float v = accQ[rt][j][r] * iq[r] + accK[rt][j][r] * ik[r] + bv;
                attn[((size_t)(b * N_ + row)) * C_ + h * HD + j * 16 + lm] = f2b(v);
            }
        }
    }
}

// ---------------------------------------------------------------------------
// Workspace layout (lifetime-aliased; high-water ~57.9 MB, well under the
// empirically-safe 74.6 MB of rounds 3/4):
//   attn          aliases xb   (xb dead after gather; score runs after gather)
//   wect/wrct/xh  alias qkwb   (qkwb dead after gemm1; wec/gather after gemm1)
// ---------------------------------------------------------------------------
extern "C" void kernel_launch(void* const* d_in, const int* in_sizes, int n_in,
                              void* d_out, int out_size, void* d_ws, size_t ws_size,
                              hipStream_t stream) {
    (void)in_sizes; (void)n_in; (void)out_size; (void)ws_size;

    char* ws = (char*)d_ws;
    size_t off = 0;
    auto alloc = [&](size_t bytes) {
        char* p = ws + off;
        off += (bytes + 255) & ~(size_t)255;
        return p;
    };

    int* flag = (int*)alloc(16);
    char* xb_region   = alloc((size_t)B_ * N_ * C_ * 2);        // 16.78 MB
    char* qkwb_region = alloc((size_t)2 * C_ * C_ * 2);         // 4.19 MB
    unsigned short* pwb   = (unsigned short*)alloc((size_t)C_ * C_ * 2);
    unsigned short* pbb   = (unsigned short*)alloc((size_t)C_ * 2);
    unsigned short* we_i  = (unsigned short*)alloc((size_t)H_ * RS * LR * 2);
    unsigned short* wr_i  = (unsigned short*)alloc((size_t)H_ * RS * LR * 2);
    unsigned short* cwwb  = (unsigned short*)alloc((size_t)HD * 2 * LR * 2);
    unsigned short* cwbb  = (unsigned short*)alloc((size_t)HD * 2);
    unsigned short* qk    = (unsigned short*)alloc((size_t)B_ * N_ * 2 * C_ * 2);  // 33.55 MB
    unsigned short* we2t  = (unsigned short*)alloc((size_t)B_ * H_ * HD * HD * 2);
    unsigned short* wr2t  = (unsigned short*)alloc((size_t)B_ * H_ * HD * HD * 2);

    // aliases
    unsigned short* xb   = (unsigned short*)xb_region;
    unsigned short* attn = (unsigned short*)xb_region;           // after gather
    unsigned short* qkwb = (unsigned short*)qkwb_region;
    unsigned short* wect = (unsigned short*)qkwb_region;                              // 458.8 KB
    unsigned short* wrct = (unsigned short*)(qkwb_region + (size_t)H_ * HD * RP * 2); // 458.8 KB
    unsigned short* xh   = (unsigned short*)(qkwb_region + (size_t)2 * H_ * HD * RP * 2); // 1.84 MB
    // wect+wrct+xh = 2.75 MB <= 4.19 MB region ✓

    const int M = B_ * N_;  // 8192

    // 0) dtype detection
    detect_kernel<<<1, 256, 0, stream>>>((const unsigned int*)d_in[0], flag);

    // 1) convert all inputs to bf16 copies
    CvtArgs ca;
    ca.src[0] = d_in[0]; ca.dst[0] = xb;   ca.size[0] = B_ * N_ * C_;
    ca.src[1] = d_in[1]; ca.dst[1] = qkwb; ca.size[1] = 2 * C_ * C_;
    ca.src[2] = d_in[2]; ca.dst[2] = pwb;  ca.size[2] = C_ * C_;
    ca.src[3] = d_in[3]; ca.dst[3] = pbb;  ca.size[3] = C_;
    ca.src[4] = d_in[4]; ca.dst[4] = we_i; ca.size[4] = H_ * RS * LR;
    ca.src[5] = d_in[5]; ca.dst[5] = wr_i; ca.size[5] = H_ * RS * LR;
    ca.src[6] = d_in[6]; ca.dst[6] = cwwb; ca.size[6] = HD * 2 * LR;
    ca.src[7] = d_in[7]; ca.dst[7] = cwbb; ca.size[7] = HD;
    convert_kernel<<<dim3(2048, 8), 256, 0, stream>>>(flag, ca);

    // 2) qk projection: [M, 2C] = x @ qk_w^T  (MFMA). Last reader of qkwb.
    gemm1_kernel<<<dim3((2 * C_) / 128, M / 128), 256, 0, stream>>>(xb, qkwb, qk);

    // 3) gen_weights, restructured (wect/wrct/xh live in old qkwb region):
    wec_kernel<<<(H_ * HD * RP + 255) / 256, 256, 0, stream>>>(
        we_i, wr_i, cwwb, wect, wrct);
    gather_kernel<<<B_ * H_, 256, 0, stream>>>(xb, xh);   // last reader of xb
    collapse_kernel<<<B_ * H_ * 4, 64, 0, stream>>>(xh, wect, wrct, we2t, wr2t);

    // 4) score+attn -> attn (lives in old xb region)
    score_attn_kernel<<<(B_ * H_ * N_ / 32) / 4, 256, 0, stream>>>(
        qk, we2t, wr2t, cwbb, attn);

    // 5) output projection: out = attn @ proj_w^T + proj_b  (MFMA)
    gemm2_kernel<<<dim3(C_ / 128, M / 128), 256, 0, stream>>>(flag, attn, pwb, pbb, d_out);
}

// Round 7
// 229.544 us; speedup vs baseline: 4.5866x; 1.0003x over previous
//
#include <hip/hip_runtime.h>
#include <hip/hip_bf16.h>

// Problem shapes (fixed by setup_inputs)
constexpr int B_  = 4;
constexpr int N_  = 2048;
constexpr int C_  = 1024;
constexpr int H_  = 16;
constexpr int HD  = 64;    // head dim
constexpr int LR  = 20;    // low rank
constexpr int RS  = 200;   // subsample length R
constexpr int RP  = 224;   // RS padded to multiple of 32 (zero-filled)

typedef __attribute__((ext_vector_type(8))) short bf16x8;
typedef __attribute__((ext_vector_type(4))) float f32x4;

__device__ __forceinline__ float b2f_raw(unsigned short u) {
    union { unsigned int i; float f; } v;
    v.i = ((unsigned int)u) << 16;
    return v.f;
}
__device__ __forceinline__ unsigned short f2b(float f) {
    __hip_bfloat16 h = __float2bfloat16(f);
    return *(unsigned short*)&h;
}

// async 16B global->LDS (wave-uniform LDS base; HW scatters lane i at +16*i)
__device__ __forceinline__ void async_load16(const unsigned short* g, unsigned short* l) {
    __builtin_amdgcn_global_load_lds(
        (const __attribute__((address_space(1))) unsigned int*)(const void*)g,
        (__attribute__((address_space(3))) unsigned int*)(void*)l,
        16, 0, 0);
}

// ---------------------------------------------------------------------------
// dtype detection: low 16 bits of fp32 words are uniform mantissa bits; of
// packed bf16 pairs they are a real bf16 sample (exponent in [103,140]).
// ---------------------------------------------------------------------------
__global__ __launch_bounds__(256)
void detect_kernel(const unsigned int* __restrict__ x, int* __restrict__ flag) {
    const int t = threadIdx.x;
    int cnt = 0;
    for (int i = t; i < 1024; i += 256) {
        const unsigned int w = x[i];
        const unsigned int e = (w >> 7) & 0xFFu;
        cnt += (e >= 103u && e <= 140u) ? 1 : 0;
    }
    __shared__ int s[256];
    s[t] = cnt;
    __syncthreads();
    for (int off = 128; off > 0; off >>= 1) {
        if (t < off) s[t] += s[t + off];
        __syncthreads();
    }
    if (t == 0) *flag = (s[0] > 512) ? 1 : 0;  // 1 = bf16 inputs, 0 = fp32
}

// ---------------------------------------------------------------------------
// Convert all 8 inputs to bf16 copies in ws. blockIdx.y selects buffer.
// ---------------------------------------------------------------------------
struct CvtArgs {
    const void* src[8];
    unsigned short* dst[8];
    int size[8];
};

__global__ __launch_bounds__(256)
void convert_kernel(const int* __restrict__ flag, CvtArgs args) {
    const int buf = blockIdx.y;
    const int n4 = args.size[buf] >> 2;
    const int stride = gridDim.x * blockDim.x;
    const bool isbf = (*flag != 0);
    for (int i = blockIdx.x * blockDim.x + threadIdx.x; i < n4; i += stride) {
        ushort4 o;
        if (isbf) {
            o = ((const ushort4*)args.src[buf])[i];
        } else {
            const float4 v = ((const float4*)args.src[buf])[i];
            o.x = f2b(v.x); o.y = f2b(v.y); o.z = f2b(v.z); o.w = f2b(v.w);
        }
        ((ushort4*)args.dst[buf])[i] = o;
    }
}

// ---------------------------------------------------------------------------
// Fused gemm1 + l2norm + score + cw projection.
// Grid (H, M/128). Block 256 = 4 waves. Block computes, for head h and rows
// [m0, m0+128): q = x@qk_w[h*64..+64]^T and k = x@qk_w[C+h*64..+64]^T
// (128x128 MFMA tile, BK=32, async LDS staging), then per-row l2 norms,
// scaled qn/kn -> LDS, then attn = qn@We2T^T + kn@Wr2T^T + cw_b -> global.
// ---------------------------------------------------------------------------
__global__ __launch_bounds__(256)
void gemm1_score_kernel(const unsigned short* __restrict__ xb,
                        const unsigned short* __restrict__ qkwb,
                        const unsigned short* __restrict__ we2t,
                        const unsigned short* __restrict__ wr2t,
                        const unsigned short* __restrict__ cwbb,
                        unsigned short* __restrict__ attn) {
    constexpr int BK = 32;
    constexpr int QS = 72;   // qn/kn row stride (16B-aligned, bank-spread)
    __shared__ __align__(16) unsigned short pool[2 * 128 * QS];  // 36 KB
    unsigned short* As = pool;               // 128*32 (phase 1)
    unsigned short* Bs = pool + 4096;        // 128*32 (phase 1)
    unsigned short* qn = pool;               // 128*QS (phase 2)
    unsigned short* kn = pool + 128 * QS;    // 128*QS (phase 2)

    const int t    = threadIdx.x;
    const int wave = t >> 6;
    const int lane = t & 63;
    const int h    = blockIdx.x;
    const int m0   = blockIdx.y * 128;
    const int K    = C_;

    // staging: chunk c (0..7) = LDS rows [c*16, c*16+16); lane l covers
    // row c*16 + l/4, cols (l%4)*8..+8. B-tile col c<64 -> qk_w row h*64+c
    // (q); c>=64 -> qk_w row C + h*64 + (c-64) (k).
    const int srow = lane >> 2;
    const int scol = (lane & 3) * 8;
    const unsigned short* ga0 = xb + (size_t)(m0 + wave * 16 + srow) * K + scol;
    const unsigned short* ga1 = xb + (size_t)(m0 + (wave + 4) * 16 + srow) * K + scol;
    const unsigned short* gb0 = qkwb + (size_t)(h * HD + wave * 16 + srow) * K + scol;
    const unsigned short* gb1 = qkwb + (size_t)(C_ + h * HD + wave * 16 + srow) * K + scol;
    unsigned short* lA0 = &As[wave * 512];
    unsigned short* lA1 = &As[(wave + 4) * 512];
    unsigned short* lB0 = &Bs[wave * 512];
    unsigned short* lB1 = &Bs[(wave + 4) * 512];

    const int wr = (wave >> 1) * 64;        // row quadrant
    const int wc = (wave & 1) * 64;         // col quadrant: 0 = q, 64 = k
    const int lq = lane >> 4;
    const int lm = lane & 15;

    f32x4 acc[4][4];
    #pragma unroll
    for (int i = 0; i < 4; ++i)
        #pragma unroll
        for (int j = 0; j < 4; ++j) acc[i][j] = 0.f;

    for (int k0 = 0; k0 < K; k0 += BK) {
        async_load16(ga0, lA0);
        async_load16(ga1, lA1);
        async_load16(gb0, lB0);
        async_load16(gb1, lB1);
        ga0 += BK; ga1 += BK; gb0 += BK; gb1 += BK;
        __syncthreads();

        bf16x8 af[4], bfr[4];
        #pragma unroll
        for (int i = 0; i < 4; ++i)
            af[i] = *(const bf16x8*)&As[(wr + i * 16 + lm) * BK + lq * 8];
        #pragma unroll
        for (int j = 0; j < 4; ++j)
            bfr[j] = *(const bf16x8*)&Bs[(wc + j * 16 + lm) * BK + lq * 8];

        #pragma unroll
        for (int i = 0; i < 4; ++i)
            #pragma unroll
            for (int j = 0; j < 4; ++j)
                acc[i][j] = __builtin_amdgcn_mfma_f32_16x16x32_bf16(
                    af[i], bfr[j], acc[i][j], 0, 0, 0);

        __syncthreads();   // also guards pool reuse below after last iter
    }

    // ---- phase 2a: per-row l2 norm + scaled bf16 store to LDS ----
    // C-layout: lane holds col j*16+lm, row wr + i*16 + lq*4 + r. All 64
    // cols of a row live in one wave (4 j-tiles x 16 lm); reduce over lm
    // with xor masks 1,2,4,8 (stay within the 16-lane lm group).
    unsigned short* dst = (wc == 0) ? qn : kn;
    #pragma unroll
    for (int i = 0; i < 4; ++i) {
        float inv[4];
        #pragma unroll
        for (int r = 0; r < 4; ++r) {
            float s = 0.f;
            #pragma unroll
            for (int j = 0; j < 4; ++j) s += acc[i][j][r] * acc[i][j][r];
            s += __shfl_xor(s, 1, 64);
            s += __shfl_xor(s, 2, 64);
            s += __shfl_xor(s, 4, 64);
            s += __shfl_xor(s, 8, 64);
            inv[r] = 1.f / fmaxf(sqrtf(s), 1e-12f);
        }
        #pragma unroll
        for (int j = 0; j < 4; ++j)
            #pragma unroll
            for (int r = 0; r < 4; ++r) {
                const int row = wr + i * 16 + lq * 4 + r;
                dst[row * QS + j * 16 + lm] = f2b(acc[i][j][r] * inv[r]);
            }
    }
    __syncthreads();

    // ---- phase 2b: attn = qn@We2T^T + kn@Wr2T^T + cw_b ----
    // (identical structure to the verified round-4 score kernel, A from LDS)
    const int b  = blockIdx.y >> 4;          // 16 row-blocks per batch
    const int bh = b * H_ + h;
    const unsigned short* wq = we2t + (size_t)bh * HD * HD;
    const unsigned short* wk = wr2t + (size_t)bh * HD * HD;

    bf16x8 bq[2][4], bk[2][4];
    #pragma unroll
    for (int t2 = 0; t2 < 2; ++t2)
        #pragma unroll
        for (int j = 0; j < 4; ++j) {
            const int dout = j * 16 + lm;
            bq[t2][j] = *(const bf16x8*)&wq[dout * HD + t2 * 32 + lq * 8];
            bk[t2][j] = *(const bf16x8*)&wk[dout * HD + t2 * 32 + lq * 8];
        }

    f32x4 accS[2][4];
    #pragma unroll
    for (int rt = 0; rt < 2; ++rt)
        #pragma unroll
        for (int j = 0; j < 4; ++j) accS[rt][j] = 0.f;

    #pragma unroll
    for (int rt = 0; rt < 2; ++rt) {
        const int lr = wave * 32 + rt * 16 + lm;   // local row, A-layout
        bf16x8 aq0 = *(const bf16x8*)&qn[lr * QS + lq * 8];
        bf16x8 aq1 = *(const bf16x8*)&qn[lr * QS + 32 + lq * 8];
        bf16x8 ak0 = *(const bf16x8*)&kn[lr * QS + lq * 8];
        bf16x8 ak1 = *(const bf16x8*)&kn[lr * QS + 32 + lq * 8];
        #pragma unroll
        for (int j = 0; j < 4; ++j) {
            accS[rt][j] = __builtin_amdgcn_mfma_f32_16x16x32_bf16(aq0, bq[0][j], accS[rt][j], 0, 0, 0);
            accS[rt][j] = __builtin_amdgcn_mfma_f32_16x16x32_bf16(aq1, bq[1][j], accS[rt][j], 0, 0, 0);
            accS[rt][j] = __builtin_amdgcn_mfma_f32_16x16x32_bf16(ak0, bk[0][j], accS[rt][j], 0, 0, 0);
            accS[rt][j] = __builtin_amdgcn_mfma_f32_16x16x32_bf16(ak1, bk[1][j], accS[rt][j], 0, 0, 0);
        }
    }

    #pragma unroll
    for (int rt = 0; rt < 2; ++rt)
        #pragma unroll
        for (int j = 0; j < 4; ++j) {
            const int dout = j * 16 + lm;
            const float bv = b2f_raw(cwbb[dout]);
            #pragma unroll
            for (int r = 0; r < 4; ++r) {
                const int row = m0 + wave * 32 + rt * 16 + lq * 4 + r;
                attn[(size_t)row * C_ + h * HD + dout] = f2b(accS[rt][j][r] + bv);
            }
        }
}

// ---------------------------------------------------------------------------
// MFMA GEMM (NT) for the output projection. 128x128 tile, BK=32.
// ---------------------------------------------------------------------------
template <bool OBF>
__device__ void mfma_gemm_body(const unsigned short* __restrict__ A,
                               const unsigned short* __restrict__ W,
                               const unsigned short* __restrict__ bias,
                               void* __restrict__ out,
                               int M, int N, int K) {
    constexpr int BM = 128, BN = 128, BK = 32;
    __shared__ __align__(16) unsigned short As[BM * BK];
    __shared__ __align__(16) unsigned short Bs[BN * BK];

    const int t    = threadIdx.x;
    const int wave = t >> 6;
    const int lane = t & 63;
    const int m0   = blockIdx.y * BM;
    const int n0   = blockIdx.x * BN;

    const int srow = lane >> 2;
    const int scol = (lane & 3) * 8;
    const unsigned short* ga0 = A + (size_t)(m0 + wave * 16 + srow) * K + scol;
    const unsigned short* ga1 = A + (size_t)(m0 + (wave + 4) * 16 + srow) * K + scol;
    const unsigned short* gb0 = W + (size_t)(n0 + wave * 16 + srow) * K + scol;
    const unsigned short* gb1 = W + (size_t)(n0 + (wave + 4) * 16 + srow) * K + scol;
    unsigned short* lA0 = &As[wave * 512];
    unsigned short* lA1 = &As[(wave + 4) * 512];
    unsigned short* lB0 = &Bs[wave * 512];
    unsigned short* lB1 = &Bs[(wave + 4) * 512];

    const int wr = (wave >> 1) * 64;
    const int wc = (wave & 1) * 64;
    const int lq = lane >> 4;
    const int lm = lane & 15;

    f32x4 acc[4][4];
    #pragma unroll
    for (int i = 0; i < 4; ++i)
        #pragma unroll
        for (int j = 0; j < 4; ++j) acc[i][j] = 0.f;

    for (int k0 = 0; k0 < K; k0 += BK) {
        async_load16(ga0, lA0);
        async_load16(ga1, lA1);
        async_load16(gb0, lB0);
        async_load16(gb1, lB1);
        ga0 += BK; ga1 += BK; gb0 += BK; gb1 += BK;
        __syncthreads();

        bf16x8 af[4], bfr[4];
        #pragma unroll
        for (int i = 0; i < 4; ++i)
            af[i] = *(const bf16x8*)&As[(wr + i * 16 + lm) * BK + lq * 8];
        #pragma unroll
        for (int j = 0; j < 4; ++j)
            bfr[j] = *(const bf16x8*)&Bs[(wc + j * 16 + lm) * BK + lq * 8];

        #pragma unroll
        for (int i = 0; i < 4; ++i)
            #pragma unroll
            for (int j = 0; j < 4; ++j)
                acc[i][j] = __builtin_amdgcn_mfma_f32_16x16x32_bf16(
                    af[i], bfr[j], acc[i][j], 0, 0, 0);

        __syncthreads();
    }

    #pragma unroll
    for (int i = 0; i < 4; ++i) {
        #pragma unroll
        for (int j = 0; j < 4; ++j) {
            const int col = n0 + wc + j * 16 + lm;
            const float bv = b2f_raw(bias[col]);
            #pragma unroll
            for (int r = 0; r < 4; ++r) {
                const int row = m0 + wr + i * 16 + lq * 4 + r;
                const float v = acc[i][j][r] + bv;
                if constexpr (OBF)
                    ((__hip_bfloat16*)out)[(size_t)row * N + col] = __float2bfloat16(v);
                else
                    ((float*)out)[(size_t)row * N + col] = v;
            }
        }
    }
}

__global__ __launch_bounds__(256)
void gemm2_kernel(const int* __restrict__ flag,
                  const unsigned short* __restrict__ attn,
                  const unsigned short* __restrict__ pwb,
                  const unsigned short* __restrict__ pbb,
                  void* __restrict__ out) {
    if (*flag) mfma_gemm_body<true>(attn, pwb, pbb, out, B_ * N_, C_, C_);
    else       mfma_gemm_body<false>(attn, pwb, pbb, out, B_ * N_, C_, C_);
}

// ---------------------------------------------------------------------------
// Stage A0: wec[h][dout][r] = sum_e we[h,r,e]*cw_w[dout,e]        (x-indep!)
//           wrc[h][dout][r] = sum_e wr[h,r,e]*cw_w[dout,20+e]
// ---------------------------------------------------------------------------
__global__ __launch_bounds__(256)
void wec_kernel(const unsigned short* __restrict__ we_in,
                const unsigned short* __restrict__ wr_in,
                const unsigned short* __restrict__ cwwb,
                unsigned short* __restrict__ wect,
                unsigned short* __restrict__ wrct) {
    const int o = blockIdx.x * 256 + threadIdx.x;
    if (o >= H_ * HD * RP) return;
    const int r    = o % RP;
    const int dout = (o / RP) % HD;
    const int h    = o / (RP * HD);
    float sq = 0.f, sk = 0.f;
    if (r < RS) {
        #pragma unroll
        for (int e = 0; e < LR; ++e) {
            const float cq = b2f_raw(cwwb[dout * 2 * LR + e]);
            const float ck = b2f_raw(cwwb[dout * 2 * LR + LR + e]);
            sq += b2f_raw(we_in[((size_t)h * RS + r) * LR + e]) * cq;
            sk += b2f_raw(wr_in[((size_t)h * RS + r) * LR + e]) * ck;
        }
    }
    wect[o] = f2b(sq);
    wrct[o] = f2b(sk);
}

// ---------------------------------------------------------------------------
// Stage A1: xh[bh][din][r] = x[b, idx[r], h*64+din], r in [0,224) zero-pad.
// idx[r] = (r*(N-1))/(R-1) exactly (trunc linspace).
// ---------------------------------------------------------------------------
__global__ __launch_bounds__(256)
void gather_kernel(const unsigned short* __restrict__ xb,
                   unsigned short* __restrict__ xh) {
    const int bh = blockIdx.x;
    const int b  = bh >> 4;
    const int h  = bh & 15;
    for (int o = threadIdx.x; o < HD * RP; o += 256) {
        const int din = o & 63;
        const int r   = o >> 6;
        unsigned short v = 0;
        if (r < RS) {
            const int ir = (r * (N_ - 1)) / (RS - 1);
            v = xb[((size_t)b * N_ + ir) * C_ + h * HD + din];
        }
        xh[(size_t)bh * HD * RP + (size_t)din * RP + r] = v;
    }
}

// ---------------------------------------------------------------------------
// Stage A2: We2T[bh][dout][din] = sum_r wec[h][dout][r] * xh[bh][din][r]
// ---------------------------------------------------------------------------
__global__ __launch_bounds__(64)
void collapse_kernel(const unsigned short* __restrict__ xh,
                     const unsigned short* __restrict__ wect,
                     const unsigned short* __restrict__ wrct,
                     unsigned short* __restrict__ we2t,
                     unsigned short* __restrict__ wr2t) {
    const int blk = blockIdx.x;
    const int bh  = blk >> 2;
    const int qk  = (blk >> 1) & 1;
    const int dh  = blk & 1;
    const int h   = bh & 15;
    const int lane = threadIdx.x;
    const int lq = lane >> 4;
    const int lm = lane & 15;

    const unsigned short* wsrc = (qk ? wrct : wect) + (size_t)h * HD * RP;
    const unsigned short* xsrc = xh + (size_t)bh * HD * RP;
    unsigned short* dst = (qk ? wr2t : we2t) + (size_t)bh * HD * HD;

    f32x4 acc[2][4];
    #pragma unroll
    for (int i = 0; i < 2; ++i)
        #pragma unroll
        for (int j = 0; j < 4; ++j) acc[i][j] = 0.f;

    for (int ks = 0; ks < RP / 32; ++ks) {
        bf16x8 a[2], bfr[4];
        #pragma unroll
        for (int rt = 0; rt < 2; ++rt)
            a[rt] = *(const bf16x8*)&wsrc[(size_t)(dh * 32 + rt * 16 + lm) * RP + ks * 32 + lq * 8];
        #pragma unroll
        for (int j = 0; j < 4; ++j)
            bfr[j] = *(const bf16x8*)&xsrc[(size_t)(j * 16 + lm) * RP + ks * 32 + lq * 8];
        #pragma unroll
        for (int rt = 0; rt < 2; ++rt)
            #pragma unroll
            for (int j = 0; j < 4; ++j)
                acc[rt][j] = __builtin_amdgcn_mfma_f32_16x16x32_bf16(
                    a[rt], bfr[j], acc[rt][j], 0, 0, 0);
    }

    #pragma unroll
    for (int rt = 0; rt < 2; ++rt)
        #pragma unroll
        for (int j = 0; j < 4; ++j)
            #pragma unroll
            for (int r = 0; r < 4; ++r) {
                const int dout = dh * 32 + rt * 16 + lq * 4 + r;
                const int din  = j * 16 + lm;
                dst[dout * HD + din] = f2b(acc[rt][j][r]);
            }
}

// ---------------------------------------------------------------------------
// No aliasing this round: qk buffer is gone, high-water ~44 MB (< proven-safe
// 57.9 MB). Order: detect -> convert -> wec/gather/collapse -> gemm1_score
// -> gemm2.
// ---------------------------------------------------------------------------
extern "C" void kernel_launch(void* const* d_in, const int* in_sizes, int n_in,
                              void* d_out, int out_size, void* d_ws, size_t ws_size,
                              hipStream_t stream) {
    (void)in_sizes; (void)n_in; (void)out_size; (void)ws_size;

    char* ws = (char*)d_ws;
    size_t off = 0;
    auto alloc = [&](size_t bytes) {
        char* p = ws + off;
        off += (bytes + 255) & ~(size_t)255;
        return p;
    };

    int* flag = (int*)alloc(16);
    unsigned short* xb    = (unsigned short*)alloc((size_t)B_ * N_ * C_ * 2);   // 16.78 MB
    unsigned short* qkwb  = (unsigned short*)alloc((size_t)2 * C_ * C_ * 2);    // 4.19 MB
    unsigned short* pwb   = (unsigned short*)alloc((size_t)C_ * C_ * 2);        // 2.10 MB
    unsigned short* pbb   = (unsigned short*)alloc((size_t)C_ * 2);
    unsigned short* we_i  = (unsigned short*)alloc((size_t)H_ * RS * LR * 2);
    unsigned short* wr_i  = (unsigned short*)alloc((size_t)H_ * RS * LR * 2);
    unsigned short* cwwb  = (unsigned short*)alloc((size_t)HD * 2 * LR * 2);
    unsigned short* cwbb  = (unsigned short*)alloc((size_t)HD * 2);
    unsigned short* attn  = (unsigned short*)alloc((size_t)B_ * N_ * C_ * 2);   // 16.78 MB
    unsigned short* we2t  = (unsigned short*)alloc((size_t)B_ * H_ * HD * HD * 2);
    unsigned short* wr2t  = (unsigned short*)alloc((size_t)B_ * H_ * HD * HD * 2);
    unsigned short* wect  = (unsigned short*)alloc((size_t)H_ * HD * RP * 2);
    unsigned short* wrct  = (unsigned short*)alloc((size_t)H_ * HD * RP * 2);
    unsigned short* xh    = (unsigned short*)alloc((size_t)B_ * H_ * HD * RP * 2);

    const int M = B_ * N_;  // 8192

    // 0) dtype detection
    detect_kernel<<<1, 256, 0, stream>>>((const unsigned int*)d_in[0], flag);

    // 1) convert all inputs to bf16 copies
    CvtArgs ca;
    ca.src[0] = d_in[0]; ca.dst[0] = xb;   ca.size[0] = B_ * N_ * C_;
    ca.src[1] = d_in[1]; ca.dst[1] = qkwb; ca.size[1] = 2 * C_ * C_;
    ca.src[2] = d_in[2]; ca.dst[2] = pwb;  ca.size[2] = C_ * C_;
    ca.src[3] = d_in[3]; ca.dst[3] = pbb;  ca.size[3] = C_;
    ca.src[4] = d_in[4]; ca.dst[4] = we_i; ca.size[4] = H_ * RS * LR;
    ca.src[5] = d_in[5]; ca.dst[5] = wr_i; ca.size[5] = H_ * RS * LR;
    ca.src[6] = d_in[6]; ca.dst[6] = cwwb; ca.size[6] = HD * 2 * LR;
    ca.src[7] = d_in[7]; ca.dst[7] = cwbb; ca.size[7] = HD;
    convert_kernel<<<dim3(2048, 8), 256, 0, stream>>>(flag, ca);

    // 2) gen_weights pipeline (must precede gemm1_score now)
    wec_kernel<<<(H_ * HD * RP + 255) / 256, 256, 0, stream>>>(
        we_i, wr_i, cwwb, wect, wrct);
    gather_kernel<<<B_ * H_, 256, 0, stream>>>(xb, xh);
    collapse_kernel<<<B_ * H_ * 4, 64, 0, stream>>>(xh, wect, wrct, we2t, wr2t);

    // 3) fused qk-projection + l2norm + score + cw projection -> attn
    gemm1_score_kernel<<<dim3(H_, M / 128), 256, 0, stream>>>(
        xb, qkwb, we2t, wr2t, cwbb, attn);

    // 4) output projection: out = attn @ proj_w^T + proj_b
    gemm2_kernel<<<dim3(C_ / 128, M / 128), 256, 0, stream>>>(flag, attn, pwb, pbb, d_out);
}